// Round 11
// baseline (431.084 us; speedup 1.0000x reference)
//
#include <hip/hip_runtime.h>
#include <hip/hip_bf16.h>

#define NN 50000
#define NE 800000
#define DH 128
#define NGRAPH 512
#define NCLS 10
#define BN_EPS 1e-5f
#define SCAN_NB ((NN + 255) / 256)   // 196
#define GEMM_NB ((NN + 63) / 64)     // 782
#define BN1_NB 1024
#define BN2_NB 32
#define FILL_SEG 392
#define FILL_NB (FILL_SEG * 8)
#define STRIPE ((NN + 7) / 8)        // 6250
#define AGG_NB ((NN / 2 + 3) / 4)    // 6250: 4 waves/block, 2 nodes/wave

typedef unsigned int uint;
typedef unsigned short ushort;
typedef __attribute__((ext_vector_type(8))) short short8;
typedef __attribute__((ext_vector_type(4))) float f32x4;

__device__ __forceinline__ ushort f2bf(float x) {
    __hip_bfloat16 h = __float2bfloat16(x);
    return *(ushort*)&h;
}
__device__ __forceinline__ float bf_lo(uint v) { return __uint_as_float(v << 16); }
__device__ __forceinline__ float bf_hi(uint v) { return __uint_as_float(v & 0xffff0000u); }

// ---------------- CSR build ----------------

// dst-range-striped histogram: count lines stay on one XCD's L2
__launch_bounds__(256)
__global__ void hist_kernel(const int* __restrict__ dst, int* __restrict__ counts, int E) {
    int stripe = blockIdx.x & 7;
    int seg = blockIdx.x >> 3;
    int lo = stripe * STRIPE;
    int hi = lo + STRIPE;
    for (int e = seg * 256 + threadIdx.x; e < E; e += FILL_SEG * 256) {
        int d = dst[e];
        if (d >= lo && d < hi) atomicAdd(&counts[d], 1);
    }
}

__launch_bounds__(256)
__global__ void scan1_kernel(const int* __restrict__ counts, int* __restrict__ bsum, int N) {
    __shared__ int ls[256];
    int i = blockIdx.x * 256 + threadIdx.x;
    ls[threadIdx.x] = (i < N) ? counts[i] : 0;
    __syncthreads();
    for (int off = 128; off > 0; off >>= 1) {
        if (threadIdx.x < off) ls[threadIdx.x] += ls[threadIdx.x + off];
        __syncthreads();
    }
    if (threadIdx.x == 0) bsum[blockIdx.x] = ls[0];
}

__launch_bounds__(256)
__global__ void scan2_kernel(int* __restrict__ bsum, int NB) {
    __shared__ int ls[256];
    int tid = threadIdx.x;
    int v = (tid < NB) ? bsum[tid] : 0;
    ls[tid] = v;
    __syncthreads();
    for (int off = 1; off < 256; off <<= 1) {
        int t = (tid >= off) ? ls[tid - off] : 0;
        __syncthreads();
        ls[tid] += t;
        __syncthreads();
    }
    if (tid < NB) bsum[tid] = ls[tid] - v;   // exclusive
}

// scan3 also emits dinv (folds old compute_dinv kernel)
__launch_bounds__(256)
__global__ void scan3_kernel(const int* __restrict__ counts, const int* __restrict__ boff,
                             int* __restrict__ offsets, int* __restrict__ cursor,
                             float* __restrict__ dinv, int N) {
    __shared__ int ls[256];
    int tid = threadIdx.x;
    int i = blockIdx.x * 256 + tid;
    int v = (i < N) ? counts[i] : 0;
    ls[tid] = v;
    __syncthreads();
    for (int off = 1; off < 256; off <<= 1) {
        int t = (tid >= off) ? ls[tid - off] : 0;
        __syncthreads();
        ls[tid] += t;
        __syncthreads();
    }
    int base = boff[blockIdx.x];
    if (i < N) {
        int ex = base + ls[tid] - v;
        offsets[i] = ex;
        cursor[i] = ex;
        dinv[i] = rsqrtf((float)(v + 1));
        if (i == N - 1) offsets[N] = base + ls[tid];
    }
}

// dst-range-striped fill
__launch_bounds__(256)
__global__ void fill_kernel(const int* __restrict__ src, const int* __restrict__ dst,
                            int* __restrict__ cursor, int* __restrict__ csr_src, int E) {
    int stripe = blockIdx.x & 7;
    int seg = blockIdx.x >> 3;
    int lo = stripe * STRIPE;
    int hi = lo + STRIPE;
    for (int e = seg * 256 + threadIdx.x; e < E; e += FILL_SEG * 256) {
        int d = dst[e];
        if (d >= lo && d < hi) {
            int pos = atomicAdd(&cursor[d], 1);
            csr_src[pos] = src[e];
        }
    }
}

// ---------------- Weight transpose+convert: WT[l][n][k] = bf16(W_l[k][n]) ----------------

__launch_bounds__(256)
__global__ void wtrans_kernel(const float* __restrict__ W1, const float* __restrict__ Wc,
                              ushort* __restrict__ WT) {
    int layer = blockIdx.x >> 4;
    int kt = (blockIdx.x >> 2) & 3, nt = blockIdx.x & 3;
    const float* W = (layer == 0) ? W1 : Wc + (size_t)(layer - 1) * DH * DH;
    __shared__ float tile[32][33];
    int t = threadIdx.x;
    int r = t >> 3;
    int c4 = (t & 7) * 4;
    float4 v = *(const float4*)&W[(size_t)(kt * 32 + r) * DH + nt * 32 + c4];
    tile[r][c4 + 0] = v.x; tile[r][c4 + 1] = v.y;
    tile[r][c4 + 2] = v.z; tile[r][c4 + 3] = v.w;
    __syncthreads();
    int n = t >> 3, k4 = (t & 7) * 4;
    ushort4 o;
    o.x = f2bf(tile[k4 + 0][n]);
    o.y = f2bf(tile[k4 + 1][n]);
    o.z = f2bf(tile[k4 + 2][n]);
    o.w = f2bf(tile[k4 + 3][n]);
    *(ushort4*)&WT[(size_t)layer * DH * DH + (size_t)(nt * 32 + n) * DH + kt * 32 + k4] = o;
}

// ---------------- MFMA GEMM: H'[r] = dinv[r] * (f(X[r]) @ W), bf16 out ----------------

template<int MODE>
__launch_bounds__(256)
__global__ void gemm_kernel(const float* __restrict__ Xf, const uint* __restrict__ Xb,
                            const ushort* __restrict__ WTl,
                            const float* __restrict__ bnacc, const float* __restrict__ gamma,
                            const float* __restrict__ beta, const float* __restrict__ dinv,
                            ushort* __restrict__ H, int N) {
    __shared__ uint4 xs4[64 * 16];    // 16 KB
    __shared__ uint4 wt4[128 * 16];   // 32 KB
    int t = threadIdx.x;
    int kc = t & 15;
    int row0 = blockIdx.x * 64;

    float sc[8], sh[8];
    if (MODE) {
        const float invN = 1.0f / (float)NN;
        #pragma unroll
        for (int j = 0; j < 8; j++) {
            int f = kc * 8 + j;
            float mean = bnacc[f] * invN;
            float var = bnacc[128 + f] * invN - mean * mean;
            float s = gamma[f] * rsqrtf(var + BN_EPS);
            sc[j] = s;
            sh[j] = beta[f] - mean * s;
        }
    }

    #pragma unroll
    for (int i = 0; i < 4; i++) {
        int row = (t >> 4) + i * 16;
        int r = row0 + row;
        float v[8];
        if (r < N) {
            if (MODE) {
                uint4 raw = ((const uint4*)Xb)[(size_t)r * 16 + kc];
                v[0] = bf_lo(raw.x); v[1] = bf_hi(raw.x);
                v[2] = bf_lo(raw.y); v[3] = bf_hi(raw.y);
                v[4] = bf_lo(raw.z); v[5] = bf_hi(raw.z);
                v[6] = bf_lo(raw.w); v[7] = bf_hi(raw.w);
                #pragma unroll
                for (int j = 0; j < 8; j++) v[j] = fmaxf(v[j] * sc[j] + sh[j], 0.f);
            } else {
                float4 a = ((const float4*)Xf)[(size_t)r * 32 + kc * 2];
                float4 b = ((const float4*)Xf)[(size_t)r * 32 + kc * 2 + 1];
                v[0] = a.x; v[1] = a.y; v[2] = a.z; v[3] = a.w;
                v[4] = b.x; v[5] = b.y; v[6] = b.z; v[7] = b.w;
            }
        } else {
            #pragma unroll
            for (int j = 0; j < 8; j++) v[j] = 0.f;
        }
        uint4 p;
        p.x = (uint)f2bf(v[0]) | ((uint)f2bf(v[1]) << 16);
        p.y = (uint)f2bf(v[2]) | ((uint)f2bf(v[3]) << 16);
        p.z = (uint)f2bf(v[4]) | ((uint)f2bf(v[5]) << 16);
        p.w = (uint)f2bf(v[6]) | ((uint)f2bf(v[7]) << 16);
        xs4[row * 16 + (kc ^ (row & 7))] = p;
    }
    const uint4* WT4 = (const uint4*)WTl;
    #pragma unroll
    for (int i = 0; i < 8; i++) {
        int n = (t >> 4) + i * 16;
        wt4[n * 16 + (kc ^ (n & 7))] = WT4[n * 16 + kc];
    }
    __syncthreads();

    int w = t >> 6, l = t & 63;
    int l16 = l >> 4;
    int lrow = w * 16 + (l & 15);
    f32x4 acc[8];
    #pragma unroll
    for (int c = 0; c < 8; c++) acc[c] = (f32x4){0.f, 0.f, 0.f, 0.f};

    #pragma unroll
    for (int ks = 0; ks < 4; ks++) {
        int kk = ks * 4 + l16;
        uint4 av = xs4[lrow * 16 + (kk ^ (lrow & 7))];
        short8 a = *(short8*)&av;
        #pragma unroll
        for (int c = 0; c < 8; c++) {
            int n = c * 16 + (l & 15);
            uint4 bv = wt4[n * 16 + (kk ^ (n & 7))];
            short8 b = *(short8*)&bv;
            acc[c] = __builtin_amdgcn_mfma_f32_16x16x32_bf16(a, b, acc[c], 0, 0, 0);
        }
    }

    #pragma unroll
    for (int j = 0; j < 4; j++) {
        int grow = row0 + w * 16 + l16 * 4 + j;
        if (grow < N) {
            float dv = dinv[grow];
            #pragma unroll
            for (int c = 0; c < 8; c++) {
                H[(size_t)grow * DH + c * 16 + (l & 15)] = f2bf(acc[c][j] * dv);
            }
        }
    }
}

// ---------------- Aggregation: out[n] = bf16(dinv[n]*(sum_e H'[src_e] + H'[n]) + b) ----------
// TWO nodes per wave, 8-deep each => 16 outstanding gathers/wave.

__launch_bounds__(256)
__global__ void agg_kernel(const uint* __restrict__ H, const int* __restrict__ offsets,
                           const int* __restrict__ csr_src, const float* __restrict__ dinv,
                           const float* __restrict__ bias, uint* __restrict__ out, int N) {
    int base = (blockIdx.x * 4 + (threadIdx.x >> 6)) * 2;
    int lane = threadIdx.x & 63;
    if (base >= N) return;
    int n0 = base, n1 = base + 1;    // NN even => n1 < N
    int e0 = offsets[n0], end0 = offsets[n0 + 1];
    int e1 = offsets[n1], end1 = offsets[n1 + 1];
    float a0x = 0.f, a0y = 0.f, a1x = 0.f, a1y = 0.f;
    while (e0 < end0 || e1 < end1) {
        uint v0[8], v1[8];
        #pragma unroll
        for (int i = 0; i < 8; i++) {
            int ee = e0 + i;
            int s = (ee < end0) ? csr_src[ee] : n0;   // csr_src padded: safe over-read
            v0[i] = H[(size_t)s * 64 + lane];
        }
        #pragma unroll
        for (int i = 0; i < 8; i++) {
            int ee = e1 + i;
            int s = (ee < end1) ? csr_src[ee] : n1;
            v1[i] = H[(size_t)s * 64 + lane];
        }
        #pragma unroll
        for (int i = 0; i < 8; i++) {
            uint w0 = (e0 + i < end0) ? v0[i] : 0u;
            uint w1 = (e1 + i < end1) ? v1[i] : 0u;
            a0x += bf_lo(w0); a0y += bf_hi(w0);
            a1x += bf_lo(w1); a1y += bf_hi(w1);
        }
        e0 += 8; e1 += 8;
    }
    float2 b = ((const float2*)bias)[lane];
    uint h0 = H[(size_t)n0 * 64 + lane];
    uint h1 = H[(size_t)n1 * 64 + lane];
    float d0 = dinv[n0], d1 = dinv[n1];
    float o0x = (a0x + bf_lo(h0)) * d0 + b.x;
    float o0y = (a0y + bf_hi(h0)) * d0 + b.y;
    float o1x = (a1x + bf_lo(h1)) * d1 + b.x;
    float o1y = (a1y + bf_hi(h1)) * d1 + b.y;
    out[(size_t)n0 * 64 + lane] = (uint)f2bf(o0x) | ((uint)f2bf(o0y) << 16);
    out[(size_t)n1 * 64 + lane] = (uint)f2bf(o1x) | ((uint)f2bf(o1y) << 16);
}

// ---------------- BatchNorm stats, two-phase, bf16 input ----------------

__launch_bounds__(256)
__global__ void bnstats1_kernel(const uint* __restrict__ A, float* __restrict__ part, int N) {
    int u = threadIdx.x & 63;
    int rh = threadIdx.x >> 6;
    float slo = 0.f, shi = 0.f, qlo = 0.f, qhi = 0.f;
    for (int r = blockIdx.x * 4 + rh; r < N; r += BN1_NB * 4) {
        uint v = A[(size_t)r * 64 + u];
        float lo = bf_lo(v), hi = bf_hi(v);
        slo += lo; shi += hi;
        qlo += lo * lo; qhi += hi * hi;
    }
    __shared__ float4 red[4][64];
    red[rh][u] = make_float4(slo, shi, qlo, qhi);
    __syncthreads();
    if (threadIdx.x < 64) {
        float4 a = red[0][u], b = red[1][u], c = red[2][u], d = red[3][u];
        float* p = part + (size_t)blockIdx.x * 256;
        p[2 * u]           = a.x + b.x + c.x + d.x;
        p[2 * u + 1]       = a.y + b.y + c.y + d.y;
        p[128 + 2 * u]     = a.z + b.z + c.z + d.z;
        p[128 + 2 * u + 1] = a.w + b.w + c.w + d.w;
    }
}

__launch_bounds__(256)
__global__ void bnstats2_kernel(const float* __restrict__ part, float* __restrict__ acc) {
    int rows = BN1_NB / BN2_NB;      // 32
    float s = 0.f;
    int r0 = blockIdx.x * rows;
    for (int r = r0; r < r0 + rows; r++) s += part[(size_t)r * 256 + threadIdx.x];
    atomicAdd(&acc[threadIdx.x], s);
}

// ---------------- Pooling with fused BN+ReLU (bf16 input) ----------------

__device__ __forceinline__ int lower_bound_dev(const int* __restrict__ a, int n, int key) {
    int lo = 0, hi = n;
    while (lo < hi) {
        int m = (lo + hi) >> 1;
        if (a[m] < key) lo = m + 1; else hi = m;
    }
    return lo;
}

__launch_bounds__(256)
__global__ void pool_kernel(const uint* __restrict__ AGG, const int* __restrict__ batch,
                            const float* __restrict__ bnacc, const float* __restrict__ gamma,
                            const float* __restrict__ beta, float* __restrict__ pooled, int N) {
    int g = blockIdx.x;
    __shared__ int sbeg, send;
    if (threadIdx.x == 0) {
        sbeg = lower_bound_dev(batch, N, g);
        send = lower_bound_dev(batch, N, g + 1);
    }
    __syncthreads();
    int beg = sbeg, end = send;
    int u = threadIdx.x & 63;
    int rh = threadIdx.x >> 6;
    const float invN = 1.0f / (float)NN;
    float m0 = bnacc[2 * u] * invN,     m1 = bnacc[2 * u + 1] * invN;
    float v0 = bnacc[128 + 2 * u] * invN - m0 * m0;
    float v1 = bnacc[128 + 2 * u + 1] * invN - m1 * m1;
    float sc0 = gamma[2 * u] * rsqrtf(v0 + BN_EPS);
    float sc1 = gamma[2 * u + 1] * rsqrtf(v1 + BN_EPS);
    float sh0 = beta[2 * u] - m0 * sc0;
    float sh1 = beta[2 * u + 1] - m1 * sc1;
    float s0 = 0.f, s1 = 0.f;
    for (int r = beg + rh; r < end; r += 4) {
        uint v = AGG[(size_t)r * 64 + u];
        s0 += fmaxf(bf_lo(v) * sc0 + sh0, 0.f);
        s1 += fmaxf(bf_hi(v) * sc1 + sh1, 0.f);
    }
    __shared__ float2 ls[4][64];
    ls[rh][u] = make_float2(s0, s1);
    __syncthreads();
    if (threadIdx.x < 64) {
        float2 a = ls[0][u], b = ls[1][u], c = ls[2][u], d = ls[3][u];
        float cnt = fmaxf((float)(end - beg), 1.f);
        pooled[g * DH + 2 * u]     = (a.x + b.x + c.x + d.x) / cnt;
        pooled[g * DH + 2 * u + 1] = (a.y + b.y + c.y + d.y) / cnt;
    }
}

// ---------------- Final linear: out = pooled @ Wl + bl ----------------

__launch_bounds__(256)
__global__ void final_kernel(const float* __restrict__ pooled, const float* __restrict__ Wl,
                             const float* __restrict__ bl, float* __restrict__ out) {
    int gid = blockIdx.x * blockDim.x + threadIdx.x;
    if (gid >= NGRAPH * NCLS) return;
    int g = gid / NCLS, c = gid % NCLS;
    float s = bl[c];
    #pragma unroll 8
    for (int k = 0; k < DH; k++) s += pooled[g * DH + k] * Wl[k * NCLS + c];
    out[gid] = s;
}

// ---------------- Launch ----------------

extern "C" void kernel_launch(void* const* d_in, const int* in_sizes, int n_in,
                              void* d_out, int out_size, void* d_ws, size_t ws_size,
                              hipStream_t stream) {
    const float* x     = (const float*)d_in[0];
    const int*   edges = (const int*)d_in[1];
    const int*   batch = (const int*)d_in[2];
    const float* W1    = (const float*)d_in[3];
    const float* b1    = (const float*)d_in[4];
    const float* g1    = (const float*)d_in[5];
    const float* be1   = (const float*)d_in[6];
    const float* Wc    = (const float*)d_in[7];
    const float* bc    = (const float*)d_in[8];
    const float* gc    = (const float*)d_in[9];
    const float* bec   = (const float*)d_in[10];
    const float* Wl    = (const float*)d_in[11];
    const float* bl    = (const float*)d_in[12];
    float* out = (float*)d_out;

    const int* esrc = edges;
    const int* edst = edges + NE;

    char* w = (char*)d_ws;
    auto alloc = [&](size_t bytes) -> void* {
        void* p = (void*)w;
        w += (bytes + 255) & ~(size_t)255;
        return p;
    };
    int*    counts  = (int*)alloc(NN * 4);
    int*    offsets = (int*)alloc((NN + 1) * 4);
    int*    cursor  = (int*)alloc(NN * 4);
    float*  dinv    = (float*)alloc(NN * 4);
    int*    csr_src = (int*)alloc(NE * 4 + 64);
    int*    bsum    = (int*)alloc(256 * 4);
    float*  bn_acc  = (float*)alloc(4 * 256 * 4);
    float*  bn_part = (float*)alloc((size_t)BN1_NB * 256 * 4);
    float*  pooled  = (float*)alloc(NGRAPH * DH * 4);
    ushort* WT      = (ushort*)alloc(4 * DH * DH * 2);
    uint*   H       = (uint*)alloc((size_t)NN * 64 * 4);
    uint*   AGG     = (uint*)alloc((size_t)NN * 64 * 4);

    hipMemsetAsync(counts, 0, NN * 4, stream);
    hipMemsetAsync(bn_acc, 0, 4 * 256 * 4, stream);
    hist_kernel<<<FILL_NB, 256, 0, stream>>>(edst, counts, NE);
    scan1_kernel<<<SCAN_NB, 256, 0, stream>>>(counts, bsum, NN);
    scan2_kernel<<<1, 256, 0, stream>>>(bsum, SCAN_NB);
    scan3_kernel<<<SCAN_NB, 256, 0, stream>>>(counts, bsum, offsets, cursor, dinv, NN);
    fill_kernel<<<FILL_NB, 256, 0, stream>>>(esrc, edst, cursor, csr_src, NE);
    wtrans_kernel<<<64, 256, 0, stream>>>(W1, Wc, WT);

    for (int l = 0; l < 4; l++) {
        const float* bm  = (l == 0) ? b1 : bc + (size_t)(l - 1) * DH;
        const float* gp  = (l == 1) ? g1 : gc + (size_t)(l - 2) * DH;
        const float* bep = (l == 1) ? be1 : bec + (size_t)(l - 2) * DH;
        const ushort* WTl = WT + (size_t)l * DH * DH;

        if (l == 0) {
            gemm_kernel<0><<<GEMM_NB, 256, 0, stream>>>(
                x, nullptr, WTl, nullptr, nullptr, nullptr, dinv, (ushort*)H, NN);
        } else {
            gemm_kernel<1><<<GEMM_NB, 256, 0, stream>>>(
                nullptr, AGG, WTl, bn_acc + (size_t)(l - 1) * 256, gp, bep, dinv,
                (ushort*)H, NN);
        }
        agg_kernel<<<AGG_NB, 256, 0, stream>>>(H, offsets, csr_src, dinv, bm, AGG, NN);
        bnstats1_kernel<<<BN1_NB, 256, 0, stream>>>(AGG, bn_part, NN);
        bnstats2_kernel<<<BN2_NB, 256, 0, stream>>>(bn_part, bn_acc + (size_t)l * 256);
    }

    pool_kernel<<<NGRAPH, 256, 0, stream>>>(AGG, batch, bn_acc + 3 * 256,
                                            gc + 2 * DH, bec + 2 * DH, pooled, NN);
    final_kernel<<<(NGRAPH * NCLS + 255) / 256, 256, 0, stream>>>(pooled, Wl, bl, out);
}

// Round 12
// 324.390 us; speedup vs baseline: 1.3289x; 1.3289x over previous
//
#include <hip/hip_runtime.h>
#include <hip/hip_bf16.h>

#define NN 50000
#define NE 800000
#define DH 128
#define NGRAPH 512
#define NCLS 10
#define BN_EPS 1e-5f
#define SCAN_NB ((NN + 255) / 256)   // 196
#define GEMM_NB ((NN + 63) / 64)     // 782
#define BN1_NB 1024
#define BN2_NB 32
#define FILL_SEG 392
#define FILL_NB (FILL_SEG * 8)
#define STRIPE ((NN + 7) / 8)        // 6250

typedef unsigned int uint;
typedef unsigned short ushort;
typedef __attribute__((ext_vector_type(8))) short short8;
typedef __attribute__((ext_vector_type(4))) float f32x4;

__device__ __forceinline__ ushort f2bf(float x) {
    __hip_bfloat16 h = __float2bfloat16(x);
    return *(ushort*)&h;
}
__device__ __forceinline__ float bf_lo(uint v) { return __uint_as_float(v << 16); }
__device__ __forceinline__ float bf_hi(uint v) { return __uint_as_float(v & 0xffff0000u); }

// ---------------- CSR build ----------------

// dst-range-striped histogram: count lines stay on one XCD's L2
__launch_bounds__(256)
__global__ void hist_kernel(const int* __restrict__ dst, int* __restrict__ counts, int E) {
    int stripe = blockIdx.x & 7;
    int seg = blockIdx.x >> 3;
    int lo = stripe * STRIPE;
    int hi = lo + STRIPE;
    for (int e = seg * 256 + threadIdx.x; e < E; e += FILL_SEG * 256) {
        int d = dst[e];
        if (d >= lo && d < hi) atomicAdd(&counts[d], 1);
    }
}

__launch_bounds__(256)
__global__ void scan1_kernel(const int* __restrict__ counts, int* __restrict__ bsum, int N) {
    __shared__ int ls[256];
    int i = blockIdx.x * 256 + threadIdx.x;
    ls[threadIdx.x] = (i < N) ? counts[i] : 0;
    __syncthreads();
    for (int off = 128; off > 0; off >>= 1) {
        if (threadIdx.x < off) ls[threadIdx.x] += ls[threadIdx.x + off];
        __syncthreads();
    }
    if (threadIdx.x == 0) bsum[blockIdx.x] = ls[0];
}

__launch_bounds__(256)
__global__ void scan2_kernel(int* __restrict__ bsum, int NB) {
    __shared__ int ls[256];
    int tid = threadIdx.x;
    int v = (tid < NB) ? bsum[tid] : 0;
    ls[tid] = v;
    __syncthreads();
    for (int off = 1; off < 256; off <<= 1) {
        int t = (tid >= off) ? ls[tid - off] : 0;
        __syncthreads();
        ls[tid] += t;
        __syncthreads();
    }
    if (tid < NB) bsum[tid] = ls[tid] - v;   // exclusive
}

// scan3 also emits dinv
__launch_bounds__(256)
__global__ void scan3_kernel(const int* __restrict__ counts, const int* __restrict__ boff,
                             int* __restrict__ offsets, int* __restrict__ cursor,
                             float* __restrict__ dinv, int N) {
    __shared__ int ls[256];
    int tid = threadIdx.x;
    int i = blockIdx.x * 256 + tid;
    int v = (i < N) ? counts[i] : 0;
    ls[tid] = v;
    __syncthreads();
    for (int off = 1; off < 256; off <<= 1) {
        int t = (tid >= off) ? ls[tid - off] : 0;
        __syncthreads();
        ls[tid] += t;
        __syncthreads();
    }
    int base = boff[blockIdx.x];
    if (i < N) {
        int ex = base + ls[tid] - v;
        offsets[i] = ex;
        cursor[i] = ex;
        dinv[i] = rsqrtf((float)(v + 1));
        if (i == N - 1) offsets[N] = base + ls[tid];
    }
}

// dst-range-striped fill
__launch_bounds__(256)
__global__ void fill_kernel(const int* __restrict__ src, const int* __restrict__ dst,
                            int* __restrict__ cursor, int* __restrict__ csr_src, int E) {
    int stripe = blockIdx.x & 7;
    int seg = blockIdx.x >> 3;
    int lo = stripe * STRIPE;
    int hi = lo + STRIPE;
    for (int e = seg * 256 + threadIdx.x; e < E; e += FILL_SEG * 256) {
        int d = dst[e];
        if (d >= lo && d < hi) {
            int pos = atomicAdd(&cursor[d], 1);
            csr_src[pos] = src[e];
        }
    }
}

// ---------------- Weight transpose+convert: WT[l][n][k] = bf16(W_l[k][n]) ----------------

__launch_bounds__(256)
__global__ void wtrans_kernel(const float* __restrict__ W1, const float* __restrict__ Wc,
                              ushort* __restrict__ WT) {
    int layer = blockIdx.x >> 4;
    int kt = (blockIdx.x >> 2) & 3, nt = blockIdx.x & 3;
    const float* W = (layer == 0) ? W1 : Wc + (size_t)(layer - 1) * DH * DH;
    __shared__ float tile[32][33];
    int t = threadIdx.x;
    int r = t >> 3;
    int c4 = (t & 7) * 4;
    float4 v = *(const float4*)&W[(size_t)(kt * 32 + r) * DH + nt * 32 + c4];
    tile[r][c4 + 0] = v.x; tile[r][c4 + 1] = v.y;
    tile[r][c4 + 2] = v.z; tile[r][c4 + 3] = v.w;
    __syncthreads();
    int n = t >> 3, k4 = (t & 7) * 4;
    ushort4 o;
    o.x = f2bf(tile[k4 + 0][n]);
    o.y = f2bf(tile[k4 + 1][n]);
    o.z = f2bf(tile[k4 + 2][n]);
    o.w = f2bf(tile[k4 + 3][n]);
    *(ushort4*)&WT[(size_t)layer * DH * DH + (size_t)(nt * 32 + n) * DH + kt * 32 + k4] = o;
}

// ---------------- MFMA GEMM: H'[r] = dinv[r] * (f(X[r]) @ W), bf16 out ----------------

template<int MODE>
__launch_bounds__(256)
__global__ void gemm_kernel(const float* __restrict__ Xf, const uint* __restrict__ Xb,
                            const ushort* __restrict__ WTl,
                            const float* __restrict__ bnacc, const float* __restrict__ gamma,
                            const float* __restrict__ beta, const float* __restrict__ dinv,
                            ushort* __restrict__ H, int N) {
    __shared__ uint4 xs4[64 * 16];    // 16 KB
    __shared__ uint4 wt4[128 * 16];   // 32 KB
    int t = threadIdx.x;
    int kc = t & 15;
    int row0 = blockIdx.x * 64;

    float sc[8], sh[8];
    if (MODE) {
        const float invN = 1.0f / (float)NN;
        #pragma unroll
        for (int j = 0; j < 8; j++) {
            int f = kc * 8 + j;
            float mean = bnacc[f] * invN;
            float var = bnacc[128 + f] * invN - mean * mean;
            float s = gamma[f] * rsqrtf(var + BN_EPS);
            sc[j] = s;
            sh[j] = beta[f] - mean * s;
        }
    }

    #pragma unroll
    for (int i = 0; i < 4; i++) {
        int row = (t >> 4) + i * 16;
        int r = row0 + row;
        float v[8];
        if (r < N) {
            if (MODE) {
                uint4 raw = ((const uint4*)Xb)[(size_t)r * 16 + kc];
                v[0] = bf_lo(raw.x); v[1] = bf_hi(raw.x);
                v[2] = bf_lo(raw.y); v[3] = bf_hi(raw.y);
                v[4] = bf_lo(raw.z); v[5] = bf_hi(raw.z);
                v[6] = bf_lo(raw.w); v[7] = bf_hi(raw.w);
                #pragma unroll
                for (int j = 0; j < 8; j++) v[j] = fmaxf(v[j] * sc[j] + sh[j], 0.f);
            } else {
                float4 a = ((const float4*)Xf)[(size_t)r * 32 + kc * 2];
                float4 b = ((const float4*)Xf)[(size_t)r * 32 + kc * 2 + 1];
                v[0] = a.x; v[1] = a.y; v[2] = a.z; v[3] = a.w;
                v[4] = b.x; v[5] = b.y; v[6] = b.z; v[7] = b.w;
            }
        } else {
            #pragma unroll
            for (int j = 0; j < 8; j++) v[j] = 0.f;
        }
        uint4 p;
        p.x = (uint)f2bf(v[0]) | ((uint)f2bf(v[1]) << 16);
        p.y = (uint)f2bf(v[2]) | ((uint)f2bf(v[3]) << 16);
        p.z = (uint)f2bf(v[4]) | ((uint)f2bf(v[5]) << 16);
        p.w = (uint)f2bf(v[6]) | ((uint)f2bf(v[7]) << 16);
        xs4[row * 16 + (kc ^ (row & 7))] = p;
    }
    const uint4* WT4 = (const uint4*)WTl;
    #pragma unroll
    for (int i = 0; i < 8; i++) {
        int n = (t >> 4) + i * 16;
        wt4[n * 16 + (kc ^ (n & 7))] = WT4[n * 16 + kc];
    }
    __syncthreads();

    int w = t >> 6, l = t & 63;
    int l16 = l >> 4;
    int lrow = w * 16 + (l & 15);
    f32x4 acc[8];
    #pragma unroll
    for (int c = 0; c < 8; c++) acc[c] = (f32x4){0.f, 0.f, 0.f, 0.f};

    #pragma unroll
    for (int ks = 0; ks < 4; ks++) {
        int kk = ks * 4 + l16;
        uint4 av = xs4[lrow * 16 + (kk ^ (lrow & 7))];
        short8 a = *(short8*)&av;
        #pragma unroll
        for (int c = 0; c < 8; c++) {
            int n = c * 16 + (l & 15);
            uint4 bv = wt4[n * 16 + (kk ^ (n & 7))];
            short8 b = *(short8*)&bv;
            acc[c] = __builtin_amdgcn_mfma_f32_16x16x32_bf16(a, b, acc[c], 0, 0, 0);
        }
    }

    #pragma unroll
    for (int j = 0; j < 4; j++) {
        int grow = row0 + w * 16 + l16 * 4 + j;
        if (grow < N) {
            float dv = dinv[grow];
            #pragma unroll
            for (int c = 0; c < 8; c++) {
                H[(size_t)grow * DH + c * 16 + (l & 15)] = f2bf(acc[c][j] * dv);
            }
        }
    }
}

// ---------------- Aggregation: out[n] = bf16(dinv[n]*(sum_e H'[src_e] + H'[n]) + b) ----------
// One node per wave; ALL batches 8-wide (masked tail — no serial remainder).

__launch_bounds__(256)
__global__ void agg_kernel(const uint* __restrict__ H, const int* __restrict__ offsets,
                           const int* __restrict__ csr_src, const float* __restrict__ dinv,
                           const float* __restrict__ bias, uint* __restrict__ out, int N) {
    int n = blockIdx.x * 4 + (threadIdx.x >> 6);
    int lane = threadIdx.x & 63;
    if (n >= N) return;
    int beg = offsets[n], end = offsets[n + 1];
    float ax = 0.f, ay = 0.f;
    for (int e = beg; e < end; e += 8) {
        uint v[8];
        #pragma unroll
        for (int i = 0; i < 8; i++) {
            int ee = e + i;
            int sraw = csr_src[ee];              // csr_src padded by 64B: safe over-read
            int s = (ee < end) ? sraw : n;       // wave-uniform select; masked -> hot row
            v[i] = H[(size_t)s * 64 + lane];
        }
        #pragma unroll
        for (int i = 0; i < 8; i++) {
            uint vv = (e + i < end) ? v[i] : 0u;
            ax += bf_lo(vv);
            ay += bf_hi(vv);
        }
    }
    uint vn = H[(size_t)n * 64 + lane];
    ax += bf_lo(vn);
    ay += bf_hi(vn);
    float dv = dinv[n];
    float2 b = ((const float2*)bias)[lane];
    float ox = ax * dv + b.x;
    float oy = ay * dv + b.y;
    out[(size_t)n * 64 + lane] = (uint)f2bf(ox) | ((uint)f2bf(oy) << 16);
}

// ---------------- BatchNorm stats, two-phase, bf16 input ----------------

__launch_bounds__(256)
__global__ void bnstats1_kernel(const uint* __restrict__ A, float* __restrict__ part, int N) {
    int u = threadIdx.x & 63;
    int rh = threadIdx.x >> 6;
    float slo = 0.f, shi = 0.f, qlo = 0.f, qhi = 0.f;
    for (int r = blockIdx.x * 4 + rh; r < N; r += BN1_NB * 4) {
        uint v = A[(size_t)r * 64 + u];
        float lo = bf_lo(v), hi = bf_hi(v);
        slo += lo; shi += hi;
        qlo += lo * lo; qhi += hi * hi;
    }
    __shared__ float4 red[4][64];
    red[rh][u] = make_float4(slo, shi, qlo, qhi);
    __syncthreads();
    if (threadIdx.x < 64) {
        float4 a = red[0][u], b = red[1][u], c = red[2][u], d = red[3][u];
        float* p = part + (size_t)blockIdx.x * 256;
        p[2 * u]           = a.x + b.x + c.x + d.x;
        p[2 * u + 1]       = a.y + b.y + c.y + d.y;
        p[128 + 2 * u]     = a.z + b.z + c.z + d.z;
        p[128 + 2 * u + 1] = a.w + b.w + c.w + d.w;
    }
}

__launch_bounds__(256)
__global__ void bnstats2_kernel(const float* __restrict__ part, float* __restrict__ acc) {
    int rows = BN1_NB / BN2_NB;      // 32
    float s = 0.f;
    int r0 = blockIdx.x * rows;
    for (int r = r0; r < r0 + rows; r++) s += part[(size_t)r * 256 + threadIdx.x];
    atomicAdd(&acc[threadIdx.x], s);
}

// ---------------- Pooling with fused BN+ReLU (bf16 input) ----------------

__device__ __forceinline__ int lower_bound_dev(const int* __restrict__ a, int n, int key) {
    int lo = 0, hi = n;
    while (lo < hi) {
        int m = (lo + hi) >> 1;
        if (a[m] < key) lo = m + 1; else hi = m;
    }
    return lo;
}

__launch_bounds__(256)
__global__ void pool_kernel(const uint* __restrict__ AGG, const int* __restrict__ batch,
                            const float* __restrict__ bnacc, const float* __restrict__ gamma,
                            const float* __restrict__ beta, float* __restrict__ pooled, int N) {
    int g = blockIdx.x;
    __shared__ int sbeg, send;
    if (threadIdx.x == 0) {
        sbeg = lower_bound_dev(batch, N, g);
        send = lower_bound_dev(batch, N, g + 1);
    }
    __syncthreads();
    int beg = sbeg, end = send;
    int u = threadIdx.x & 63;
    int rh = threadIdx.x >> 6;
    const float invN = 1.0f / (float)NN;
    float m0 = bnacc[2 * u] * invN,     m1 = bnacc[2 * u + 1] * invN;
    float v0 = bnacc[128 + 2 * u] * invN - m0 * m0;
    float v1 = bnacc[128 + 2 * u + 1] * invN - m1 * m1;
    float sc0 = gamma[2 * u] * rsqrtf(v0 + BN_EPS);
    float sc1 = gamma[2 * u + 1] * rsqrtf(v1 + BN_EPS);
    float sh0 = beta[2 * u] - m0 * sc0;
    float sh1 = beta[2 * u + 1] - m1 * sc1;
    float s0 = 0.f, s1 = 0.f;
    for (int r = beg + rh; r < end; r += 4) {
        uint v = AGG[(size_t)r * 64 + u];
        s0 += fmaxf(bf_lo(v) * sc0 + sh0, 0.f);
        s1 += fmaxf(bf_hi(v) * sc1 + sh1, 0.f);
    }
    __shared__ float2 ls[4][64];
    ls[rh][u] = make_float2(s0, s1);
    __syncthreads();
    if (threadIdx.x < 64) {
        float2 a = ls[0][u], b = ls[1][u], c = ls[2][u], d = ls[3][u];
        float cnt = fmaxf((float)(end - beg), 1.f);
        pooled[g * DH + 2 * u]     = (a.x + b.x + c.x + d.x) / cnt;
        pooled[g * DH + 2 * u + 1] = (a.y + b.y + c.y + d.y) / cnt;
    }
}

// ---------------- Final linear: out = pooled @ Wl + bl ----------------

__launch_bounds__(256)
__global__ void final_kernel(const float* __restrict__ pooled, const float* __restrict__ Wl,
                             const float* __restrict__ bl, float* __restrict__ out) {
    int gid = blockIdx.x * blockDim.x + threadIdx.x;
    if (gid >= NGRAPH * NCLS) return;
    int g = gid / NCLS, c = gid % NCLS;
    float s = bl[c];
    #pragma unroll 8
    for (int k = 0; k < DH; k++) s += pooled[g * DH + k] * Wl[k * NCLS + c];
    out[gid] = s;
}

// ---------------- Launch ----------------

extern "C" void kernel_launch(void* const* d_in, const int* in_sizes, int n_in,
                              void* d_out, int out_size, void* d_ws, size_t ws_size,
                              hipStream_t stream) {
    const float* x     = (const float*)d_in[0];
    const int*   edges = (const int*)d_in[1];
    const int*   batch = (const int*)d_in[2];
    const float* W1    = (const float*)d_in[3];
    const float* b1    = (const float*)d_in[4];
    const float* g1    = (const float*)d_in[5];
    const float* be1   = (const float*)d_in[6];
    const float* Wc    = (const float*)d_in[7];
    const float* bc    = (const float*)d_in[8];
    const float* gc    = (const float*)d_in[9];
    const float* bec   = (const float*)d_in[10];
    const float* Wl    = (const float*)d_in[11];
    const float* bl    = (const float*)d_in[12];
    float* out = (float*)d_out;

    const int* esrc = edges;
    const int* edst = edges + NE;

    char* w = (char*)d_ws;
    auto alloc = [&](size_t bytes) -> void* {
        void* p = (void*)w;
        w += (bytes + 255) & ~(size_t)255;
        return p;
    };
    int*    counts  = (int*)alloc(NN * 4);
    int*    offsets = (int*)alloc((NN + 1) * 4);
    int*    cursor  = (int*)alloc(NN * 4);
    float*  dinv    = (float*)alloc(NN * 4);
    int*    csr_src = (int*)alloc(NE * 4 + 64);
    int*    bsum    = (int*)alloc(256 * 4);
    float*  bn_acc  = (float*)alloc(4 * 256 * 4);
    float*  bn_part = (float*)alloc((size_t)BN1_NB * 256 * 4);
    float*  pooled  = (float*)alloc(NGRAPH * DH * 4);
    ushort* WT      = (ushort*)alloc(4 * DH * DH * 2);
    uint*   H       = (uint*)alloc((size_t)NN * 64 * 4);
    uint*   AGG     = (uint*)alloc((size_t)NN * 64 * 4);

    hipMemsetAsync(counts, 0, NN * 4, stream);
    hipMemsetAsync(bn_acc, 0, 4 * 256 * 4, stream);
    hist_kernel<<<FILL_NB, 256, 0, stream>>>(edst, counts, NE);
    scan1_kernel<<<SCAN_NB, 256, 0, stream>>>(counts, bsum, NN);
    scan2_kernel<<<1, 256, 0, stream>>>(bsum, SCAN_NB);
    scan3_kernel<<<SCAN_NB, 256, 0, stream>>>(counts, bsum, offsets, cursor, dinv, NN);
    fill_kernel<<<FILL_NB, 256, 0, stream>>>(esrc, edst, cursor, csr_src, NE);
    wtrans_kernel<<<64, 256, 0, stream>>>(W1, Wc, WT);

    for (int l = 0; l < 4; l++) {
        const float* bm  = (l == 0) ? b1 : bc + (size_t)(l - 1) * DH;
        const float* gp  = (l == 1) ? g1 : gc + (size_t)(l - 2) * DH;
        const float* bep = (l == 1) ? be1 : bec + (size_t)(l - 2) * DH;
        const ushort* WTl = WT + (size_t)l * DH * DH;

        if (l == 0) {
            gemm_kernel<0><<<GEMM_NB, 256, 0, stream>>>(
                x, nullptr, WTl, nullptr, nullptr, nullptr, dinv, (ushort*)H, NN);
        } else {
            gemm_kernel<1><<<GEMM_NB, 256, 0, stream>>>(
                nullptr, AGG, WTl, bn_acc + (size_t)(l - 1) * 256, gp, bep, dinv,
                (ushort*)H, NN);
        }
        agg_kernel<<<(NN + 3) / 4, 256, 0, stream>>>(H, offsets, csr_src, dinv, bm, AGG, NN);
        bnstats1_kernel<<<BN1_NB, 256, 0, stream>>>(AGG, bn_part, NN);
        bnstats2_kernel<<<BN2_NB, 256, 0, stream>>>(bn_part, bn_acc + (size_t)l * 256);
    }

    pool_kernel<<<NGRAPH, 256, 0, stream>>>(AGG, batch, bn_acc + 3 * 256,
                                            gc + 2 * DH, bec + 2 * DH, pooled, NN);
    final_kernel<<<(NGRAPH * NCLS + 255) / 256, 256, 0, stream>>>(pooled, Wl, bl, out);
}